// Round 1
// baseline (764.461 us; speedup 1.0000x reference)
//
#include <hip/hip_runtime.h>
#include <hip/hip_bf16.h>
#include <cstdint>

typedef __attribute__((ext_vector_type(8))) short short8;
typedef __attribute__((ext_vector_type(4))) float f32x4;
typedef _Float16 f16x2 __attribute__((ext_vector_type(2)));

#define NS 512
#define NB 32
#define NE 768
#define NH 128
#define NG 512          // 4*H
#define NT 15
#define NM (NB*NS)      // 16384 rows, m = b*512 + s

__device__ __forceinline__ float fd2(unsigned int wp, unsigned int hp, float acc) {
#if __has_builtin(__builtin_amdgcn_fdot2)
  return __builtin_amdgcn_fdot2(__builtin_bit_cast(f16x2, wp),
                                __builtin_bit_cast(f16x2, hp), acc, false);
#else
  f16x2 a = __builtin_bit_cast(f16x2, wp);
  f16x2 b = __builtin_bit_cast(f16x2, hp);
  return acc + (float)a[0]*(float)b[0] + (float)a[1]*(float)b[1];
#endif
}

// ---------------- converts ----------------
__global__ void cvt_bf16_kernel(const float* __restrict__ in,
                                __hip_bfloat16* __restrict__ out, int n4) {
  int i = blockIdx.x*blockDim.x + threadIdx.x;
  int stride = gridDim.x*blockDim.x;
  for (int j = i; j < n4; j += stride) {
    float4 v = ((const float4*)in)[j];
    __hip_bfloat16 h0 = __float2bfloat16(v.x), h1 = __float2bfloat16(v.y),
                   h2 = __float2bfloat16(v.z), h3 = __float2bfloat16(v.w);
    ushort4 o;
    o.x = __builtin_bit_cast(unsigned short, h0);
    o.y = __builtin_bit_cast(unsigned short, h1);
    o.z = __builtin_bit_cast(unsigned short, h2);
    o.w = __builtin_bit_cast(unsigned short, h3);
    ((ushort4*)out)[j] = o;
  }
}

__global__ void cvt_f16_kernel(const float* __restrict__ in,
                               _Float16* __restrict__ out, int n4) {
  int i = blockIdx.x*blockDim.x + threadIdx.x;
  int stride = gridDim.x*blockDim.x;
  for (int j = i; j < n4; j += stride) {
    float4 v = ((const float4*)in)[j];
    _Float16 h0 = (_Float16)v.x, h1 = (_Float16)v.y,
             h2 = (_Float16)v.z, h3 = (_Float16)v.w;
    ushort4 o;
    o.x = __builtin_bit_cast(unsigned short, h0);
    o.y = __builtin_bit_cast(unsigned short, h1);
    o.z = __builtin_bit_cast(unsigned short, h2);
    o.w = __builtin_bit_cast(unsigned short, h3);
    ((ushort4*)out)[j] = o;
  }
}

__global__ void bias_kernel(const float* __restrict__ bihf, const float* __restrict__ bhhf,
                            const float* __restrict__ bihb, const float* __restrict__ bhhb,
                            float* __restrict__ bias) {
  int i = blockIdx.x*blockDim.x + threadIdx.x;
  if (i < 512)       bias[i] = bihf[i] + bhhf[i];
  else if (i < 1024) bias[i] = bihb[i-512] + bhhb[i-512];
}

// ---------------- xproj GEMM: [16384x768]bf16 @ [1024x768]^T bf16 -> bf16 ----------------
// 128x128 tile, BK=64, 4 waves (2x2), reg-staged LDS (compile-safe round-1 path).
__global__ __launch_bounds__(256, 2) void gemm_xproj(
    const __hip_bfloat16* __restrict__ A,    // [NM][768] rows m=(b,s)
    const __hip_bfloat16* __restrict__ Bw,   // [1024][768] rows n (B^T layout)
    const float* __restrict__ bias,          // [1024] bih+bhh per n
    __hip_bfloat16* __restrict__ xprojF,     // [NM][512]
    __hip_bfloat16* __restrict__ xprojB)     // [NM][512]
{
  __shared__ __align__(16) __hip_bfloat16 As[128*64];
  __shared__ __align__(16) __hip_bfloat16 Bs[128*64];
  const int bm = blockIdx.x * 128;
  const int bn = blockIdx.y * 128;
  const int tid = threadIdx.x;
  const int lane = tid & 63;
  const int wv = tid >> 6;
  const int wr = wv >> 1, wc = wv & 1;
  char* AsB = (char*)As;
  char* BsB = (char*)Bs;
  const char* Ab = (const char*)A;
  const char* Bb = (const char*)Bw;
  f32x4 acc[4][4] = {};

  for (int kt = 0; kt < 12; ++kt) {
    const int k0 = kt * 64;
    uint4 ar[4], br[4];
    #pragma unroll
    for (int i = 0; i < 4; ++i) {
      int fb = i*4096 + tid*16;       // byte within 16KB tile
      int r  = fb >> 7;               // row (128B per row of 64 bf16)
      int cb = fb & 127;              // byte within row
      ar[i] = *(const uint4*)(Ab + ((size_t)(bm + r)*768 + k0)*2 + cb);
      br[i] = *(const uint4*)(Bb + ((size_t)(bn + r)*768 + k0)*2 + cb);
    }
    __syncthreads();                  // prev compute done before overwrite
    #pragma unroll
    for (int i = 0; i < 4; ++i) {
      int fb = i*4096 + tid*16;
      *(uint4*)(AsB + fb) = ar[i];
      *(uint4*)(BsB + fb) = br[i];
    }
    __syncthreads();
    #pragma unroll
    for (int ks = 0; ks < 2; ++ks) {
      const int krow = ks*32 + ((lane >> 4) << 3);
      short8 af[4], bfr[4];
      #pragma unroll
      for (int m = 0; m < 4; ++m) {
        int row = wr*64 + m*16 + (lane & 15);
        af[m] = *(const short8*)(AsB + (row*64 + krow)*2);
      }
      #pragma unroll
      for (int n = 0; n < 4; ++n) {
        int row = wc*64 + n*16 + (lane & 15);
        bfr[n] = *(const short8*)(BsB + (row*64 + krow)*2);
      }
      #pragma unroll
      for (int m = 0; m < 4; ++m)
        #pragma unroll
        for (int n = 0; n < 4; ++n)
          acc[m][n] = __builtin_amdgcn_mfma_f32_16x16x32_bf16(af[m], bfr[n], acc[m][n], 0, 0, 0);
    }
  }
  // epilogue: C/D layout col=lane&15, row=(lane>>4)*4+reg (m89-verified)
  #pragma unroll
  for (int m = 0; m < 4; ++m) {
    #pragma unroll
    for (int n = 0; n < 4; ++n) {
      const int col = bn + wc*64 + n*16 + (lane & 15);
      const float bv = bias[col];
      #pragma unroll
      for (int jj = 0; jj < 4; ++jj) {
        const int row = bm + wr*64 + m*16 + ((lane >> 4)*4 + jj);
        __hip_bfloat16 o = __float2bfloat16(acc[m][n][jj] + bv);
        if (col < 512) xprojF[(size_t)row*512 + col] = o;
        else           xprojB[(size_t)row*512 + (col - 512)] = o;
      }
    }
  }
}

// ---------------- LSTM recurrence: 64 blocks = (dir, b) chains ----------------
__global__ __launch_bounds__(256, 1) void lstm_kernel(
    const __hip_bfloat16* __restrict__ xproj, // [2][NM][512]
    const _Float16* __restrict__ whh16,       // [2][512][128]
    float* __restrict__ hf,                   // [NM][128]
    float* __restrict__ hb)                   // [NM][128]
{
  __shared__ __align__(16) _Float16 hsh[128];
  __shared__ float zsh[512];
  const int bid = blockIdx.x;
  const int dir = bid >> 5, b = bid & 31;
  const int t = threadIdx.x;
  const int r0 = t, r1 = t + 256;

  // Whh rows r0, r1 resident in VGPRs as f16 pairs
  unsigned int w0[64], w1[64];
  {
    const uint4* w0p = (const uint4*)(whh16 + ((size_t)dir*512 + r0)*128);
    const uint4* w1p = (const uint4*)(whh16 + ((size_t)dir*512 + r1)*128);
    #pragma unroll
    for (int i = 0; i < 16; ++i) {
      uint4 a = w0p[i]; uint4 c2 = w1p[i];
      w0[i*4+0]=a.x;  w0[i*4+1]=a.y;  w0[i*4+2]=a.z;  w0[i*4+3]=a.w;
      w1[i*4+0]=c2.x; w1[i*4+1]=c2.y; w1[i*4+2]=c2.z; w1[i*4+3]=c2.w;
    }
  }
  if (t < 128) hsh[t] = (_Float16)0.f;
  float c = 0.f;
  __syncthreads();

  const __hip_bfloat16* xp = xproj + ((size_t)dir*NM + (size_t)b*512)*512;
  float* hout = dir ? hb : hf;

  float zx0, zx1;
  {
    int s0 = dir ? 511 : 0;
    zx0 = (float)xp[(size_t)s0*512 + r0];
    zx1 = (float)xp[(size_t)s0*512 + r1];
  }
  for (int si = 0; si < 512; ++si) {
    const int s = dir ? (511 - si) : si;
    float cur0 = zx0, cur1 = zx1;
    if (si < 511) {                     // prefetch next step's xproj
      int sn = dir ? (510 - si) : (si + 1);
      zx0 = (float)xp[(size_t)sn*512 + r0];
      zx1 = (float)xp[(size_t)sn*512 + r1];
    }
    float acc0 = cur0, acc1 = cur1;     // bias folded into xproj by GEMM
    const uint4* h4 = (const uint4*)hsh;
    #pragma unroll
    for (int i = 0; i < 16; ++i) {
      uint4 hv = h4[i];
      acc0 = fd2(w0[i*4+0], hv.x, acc0);
      acc1 = fd2(w1[i*4+0], hv.x, acc1);
      acc0 = fd2(w0[i*4+1], hv.y, acc0);
      acc1 = fd2(w1[i*4+1], hv.y, acc1);
      acc0 = fd2(w0[i*4+2], hv.z, acc0);
      acc1 = fd2(w1[i*4+2], hv.z, acc1);
      acc0 = fd2(w0[i*4+3], hv.w, acc0);
      acc1 = fd2(w1[i*4+3], hv.w, acc1);
    }
    zsh[r0] = acc0;
    zsh[r1] = acc1;
    __syncthreads();
    if (t < 128) {
      float zi = zsh[t], zf = zsh[t+128], zg = zsh[t+256], zo = zsh[t+384];
      float I  = __fdividef(1.f, 1.f + __expf(-zi));
      float F  = __fdividef(1.f, 1.f + __expf(-zf));
      float Gv = 1.f - __fdividef(2.f, __expf(2.f*zg) + 1.f);
      float O  = __fdividef(1.f, 1.f + __expf(-zo));
      c = F*c + I*Gv;
      float hvf = O * (1.f - __fdividef(2.f, __expf(2.f*c) + 1.f));
      hout[((size_t)b*512 + s)*128 + t] = hvf;
      hsh[t] = (_Float16)hvf;
    }
    __syncthreads();
  }
}

// ---------------- emissions: em[m][t] = [hf|hb][m] . Wp[t] + bp[t] ----------------
__global__ __launch_bounds__(256) void em_kernel(
    const float* __restrict__ hf, const float* __restrict__ hb,
    const float* __restrict__ Wp, const float* __restrict__ bp,
    float* __restrict__ em)
{
  __shared__ float wps[15*256];
  __shared__ float bps[15];
  const int tid = threadIdx.x;
  for (int i = tid; i < 15*256; i += 256) wps[i] = Wp[i];
  if (tid < 15) bps[tid] = bp[tid];
  __syncthreads();
  const size_t m = (size_t)blockIdx.x*256 + tid;
  float acc[15];
  #pragma unroll
  for (int t2 = 0; t2 < 15; ++t2) acc[t2] = bps[t2];
  const float4* hf4 = (const float4*)(hf + m*128);
  const float4* hb4 = (const float4*)(hb + m*128);
  for (int kc = 0; kc < 32; ++kc) {
    float4 hv = hf4[kc];
    #pragma unroll
    for (int t2 = 0; t2 < 15; ++t2)
      acc[t2] += hv.x*wps[t2*256 + kc*4+0] + hv.y*wps[t2*256 + kc*4+1]
               + hv.z*wps[t2*256 + kc*4+2] + hv.w*wps[t2*256 + kc*4+3];
  }
  for (int kc = 0; kc < 32; ++kc) {
    float4 hv = hb4[kc];
    #pragma unroll
    for (int t2 = 0; t2 < 15; ++t2)
      acc[t2] += hv.x*wps[t2*256 + 128 + kc*4+0] + hv.y*wps[t2*256 + 128 + kc*4+1]
               + hv.z*wps[t2*256 + 128 + kc*4+2] + hv.w*wps[t2*256 + 128 + kc*4+3];
  }
  float* eo = em + m*15;
  #pragma unroll
  for (int t2 = 0; t2 < 15; ++t2) eo[t2] = acc[t2];
}

// ---------------- CRF NLL: one block (1 wave) per batch ----------------
__global__ __launch_bounds__(64) void crf_kernel(
    const float* __restrict__ em,    // [NM][15], m=b*512+s
    const int* __restrict__ tags, const int* __restrict__ mask,
    const float* __restrict__ trans, const float* __restrict__ start_t,
    const float* __restrict__ end_t, float* __restrict__ out)
{
  __shared__ __align__(16) float ems[512*15];
  __shared__ float trs[225];
  __shared__ int tgs[512];
  __shared__ int mks[512];
  const int b = blockIdx.x, j = threadIdx.x;
  const float* emb = em + (size_t)b*512*15;
  {
    const float4* s4 = (const float4*)emb;
    float4* d4 = (float4*)ems;
    for (int i = j; i < 512*15/4; i += 64) d4[i] = s4[i];
    for (int i = j; i < 512; i += 64) { tgs[i] = tags[b*512+i]; mks[i] = mask[b*512+i]; }
    for (int i = j; i < 225; i += 64) trs[i] = trans[i];
  }
  __syncthreads();

  float trc[15];
  #pragma unroll
  for (int i = 0; i < 15; ++i) trc[i] = (j < 15) ? trs[i*15 + j] : 0.f;

  float alpha = (j < 15) ? (start_t[j] + ems[j]) : -3.0e38f;
  for (int s = 1; s < 512; ++s) {
    float emv = (j < 15) ? ems[s*15 + j] : 0.f;
    int msk = mks[s];
    float v[15]; float mx = -3.0e38f;
    #pragma unroll
    for (int i = 0; i < 15; ++i) {
      float ai = __shfl(alpha, i, 64);
      v[i] = ai + trc[i];
      mx = fmaxf(mx, v[i]);
    }
    float sum = 0.f;
    #pragma unroll
    for (int i = 0; i < 15; ++i) sum += __expf(v[i] - mx);
    float nxt = emv + mx + __logf(sum);
    if (msk > 0 && j < 15) alpha = nxt;
  }
  // logZ = LSE_j(alpha + end_t)
  float vz = (j < 15) ? (alpha + end_t[j]) : -3.0e38f;
  float mz = vz;
  #pragma unroll
  for (int off = 32; off > 0; off >>= 1) mz = fmaxf(mz, __shfl_xor(mz, off, 64));
  float se = (j < 15) ? __expf(vz - mz) : 0.f;
  #pragma unroll
  for (int off = 32; off > 0; off >>= 1) se += __shfl_xor(se, off, 64);
  float logZ = mz + __logf(se);

  // gold-path score
  float sc = 0.f; int cnt = 0;
  for (int s = j; s < 512; s += 64) cnt += (mks[s] ? 1 : 0);
  for (int s = 1 + j; s < 512; s += 64) {
    if (mks[s]) {
      int tp = tgs[s-1], tc = tgs[s];
      sc += trs[tp*15 + tc] + ems[s*15 + tc];
    }
  }
  #pragma unroll
  for (int off = 32; off > 0; off >>= 1) {
    sc  += __shfl_xor(sc, off, 64);
    cnt += __shfl_xor(cnt, off, 64);
  }
  if (j == 0) {
    int t0 = tgs[0];
    sc += start_t[t0] + ems[t0];
    int last = cnt - 1; if (last < 0) last = 0;
    sc += end_t[tgs[last]];
    atomicAdd(out, logZ - sc);
  }
}

// ---------------- launch ----------------
extern "C" void kernel_launch(void* const* d_in, const int* in_sizes, int n_in,
                              void* d_out, int out_size, void* d_ws, size_t ws_size,
                              hipStream_t stream) {
  const float* x      = (const float*)d_in[0];
  const int*   tags   = (const int*)d_in[1];
  const int*   mask   = (const int*)d_in[2];
  const float* Wih_f  = (const float*)d_in[3];
  const float* Whh_f  = (const float*)d_in[4];
  const float* bih_f  = (const float*)d_in[5];
  const float* bhh_f  = (const float*)d_in[6];
  const float* Wih_b  = (const float*)d_in[7];
  const float* Whh_b  = (const float*)d_in[8];
  const float* bih_b  = (const float*)d_in[9];
  const float* bhh_b  = (const float*)d_in[10];
  const float* Wp     = (const float*)d_in[11];
  const float* bp     = (const float*)d_in[12];
  const float* trans  = (const float*)d_in[13];
  const float* start_t= (const float*)d_in[14];
  const float* end_t  = (const float*)d_in[15];
  float* out = (float*)d_out;

  char* ws = (char*)d_ws;
  size_t off = 0;
  auto alloc = [&](size_t bytes) { char* p = ws + off; off += (bytes + 255) & ~(size_t)255; return p; };
  __hip_bfloat16* xbf   = (__hip_bfloat16*)alloc((size_t)NM*NE*2);        // 25.2 MB
  __hip_bfloat16* Wihbf = (__hip_bfloat16*)alloc((size_t)1024*NE*2);      // 1.6 MB
  _Float16*       whh16 = (_Float16*)alloc((size_t)2*512*128*2);          // 0.26 MB
  float*          bias  = (float*)alloc(1024*4);
  __hip_bfloat16* xproj = (__hip_bfloat16*)alloc((size_t)2*NM*512*2);     // 33.6 MB
  float*          hf    = (float*)alloc((size_t)NM*128*4);                // 8.4 MB
  float*          hb    = (float*)alloc((size_t)NM*128*4);                // 8.4 MB
  float*          em    = (float*)alloc((size_t)NM*15*4);                 // 1.0 MB
  (void)ws_size; (void)in_sizes; (void)n_in;

  hipMemsetAsync(d_out, 0, (size_t)out_size*sizeof(float), stream);

  cvt_bf16_kernel<<<2048, 256, 0, stream>>>(x, xbf, NM*NE/4);
  cvt_bf16_kernel<<<256, 256, 0, stream>>>(Wih_f, Wihbf, 512*768/4);
  cvt_bf16_kernel<<<256, 256, 0, stream>>>(Wih_b, Wihbf + 512*768, 512*768/4);
  cvt_f16_kernel<<<64, 256, 0, stream>>>(Whh_f, whh16, 512*128/4);
  cvt_f16_kernel<<<64, 256, 0, stream>>>(Whh_b, whh16 + 512*128, 512*128/4);
  bias_kernel<<<4, 256, 0, stream>>>(bih_f, bhh_f, bih_b, bhh_b, bias);

  gemm_xproj<<<dim3(128, 8), 256, 0, stream>>>(xbf, Wihbf, bias, xproj, xproj + (size_t)NM*512);
  lstm_kernel<<<64, 256, 0, stream>>>(xproj, whh16, hf, hb);
  em_kernel<<<64, 256, 0, stream>>>(hf, hb, Wp, bp, em);
  crf_kernel<<<32, 64, 0, stream>>>(em, tags, mask, trans, start_t, end_t, out);
}